// Round 1
// baseline (152.593 us; speedup 1.0000x reference)
//
#include <hip/hip_runtime.h>
#include <math.h>

#define N_NODES 204800
#define B_GRAPHS 4096
#define DIM 128

__device__ __forceinline__ float sigf(float x) {
    return 1.0f / (1.0f + __expf(-x));
}

// ---------------------------------------------------------------------------
// Kernel 1: q[b][d] = U_feat[b] @ W_user + b_user + feat_i[last_nodes[b]] @ W_last
// 512 blocks x 128 threads, 8 graphs per block. W rows streamed (coalesced),
// U/L rows staged in LDS and read back as broadcast float4s.
// ---------------------------------------------------------------------------
__global__ __launch_bounds__(128) void qkernel(
    const float* __restrict__ feat, const float* __restrict__ U_feat,
    const float* __restrict__ W_user, const float* __restrict__ b_user,
    const float* __restrict__ W_last, const int* __restrict__ last_nodes,
    float* __restrict__ q) {
  __shared__ float sU[8][DIM];
  __shared__ float sL[8][DIM];
  const int d = threadIdx.x;
  const int g0 = blockIdx.x * 8;
  for (int g = 0; g < 8; ++g) {
    sU[g][d] = U_feat[(g0 + g) * DIM + d];
    int ln = last_nodes[g0 + g];
    sL[g][d] = feat[ln * DIM + d];
  }
  __syncthreads();
  float acc[8];
#pragma unroll
  for (int g = 0; g < 8; ++g) acc[g] = 0.0f;

  for (int kk = 0; kk < 32; ++kk) {
    float wu[4], wl[4];
#pragma unroll
    for (int j = 0; j < 4; ++j) {
      wu[j] = W_user[(kk * 4 + j) * DIM + d];
      wl[j] = W_last[(kk * 4 + j) * DIM + d];
    }
#pragma unroll
    for (int g = 0; g < 8; ++g) {
      float4 u4 = reinterpret_cast<const float4*>(sU[g])[kk];
      float4 l4 = reinterpret_cast<const float4*>(sL[g])[kk];
      acc[g] += u4.x * wu[0] + u4.y * wu[1] + u4.z * wu[2] + u4.w * wu[3];
      acc[g] += l4.x * wl[0] + l4.y * wl[1] + l4.z * wl[2] + l4.w * wl[3];
    }
  }
  float bu = b_user[d];
  for (int g = 0; g < 8; ++g) q[(g0 + g) * DIM + d] = acc[g] + bu;
}

// ---------------------------------------------------------------------------
// Kernel 2: e[n] = sigmoid(q[seg[n]] + feat_i[n] @ W_key) . w_e + log(cnt[n])
// 1600 blocks x 256 threads. Tile: 128 nodes x 128 cols, K split in 2 halves
// of 64 so LDS = 32KB (A^T) + 32KB (W) = 64KB -> 2 blocks/CU.
// Thread (tx,ty): tx=tid&15, ty=tid>>4. Nodes ty*8..+7, cols {tx*4..+3} and
// {64+tx*4..+3}. Inner loop: 4 ds_read_b128 + 64 FMA -> VALU-bound.
// ---------------------------------------------------------------------------
__global__ __launch_bounds__(256) void ekernel(
    const float* __restrict__ feat, const float* __restrict__ W_key,
    const float* __restrict__ w_e, const float* __restrict__ cnt,
    const int* __restrict__ seg, const float* __restrict__ q,
    float* __restrict__ e) {
  __shared__ float sA[64 * DIM];  // [k_local][node]  (transposed A)
  __shared__ float sW[64 * DIM];  // [k_local][col]
  const int tid = threadIdx.x;
  const int tx = tid & 15;
  const int ty = tid >> 4;
  const int base = blockIdx.x * 128;

  float4 acc[8], acc2[8];
#pragma unroll
  for (int j = 0; j < 8; ++j) {
    acc[j] = float4{0.f, 0.f, 0.f, 0.f};
    acc2[j] = float4{0.f, 0.f, 0.f, 0.f};
  }

  const float4* feat4 = reinterpret_cast<const float4*>(feat);
  const float4* Wk4 = reinterpret_cast<const float4*>(W_key);
  const float4* sA4 = reinterpret_cast<const float4*>(sA);
  const float4* sW4 = reinterpret_cast<const float4*>(sW);
  float4* sW4w = reinterpret_cast<float4*>(sW);

  for (int kb = 0; kb < 2; ++kb) {
    __syncthreads();
    // Stage A transposed + W linear. flat = tid + it*256.
    // n = flat&127 (lanes -> consecutive nodes => LDS writes 2-way/free),
    // kc = flat>>7.
#pragma unroll
    for (int it = 0; it < 8; ++it) {
      int flat = tid + it * 256;
      int n = flat & 127;
      int kc = flat >> 7;  // 0..15 (float4 chunk along k)
      float4 v = feat4[(base + n) * 32 + kb * 16 + kc];
      sA[(kc * 4 + 0) * DIM + n] = v.x;
      sA[(kc * 4 + 1) * DIM + n] = v.y;
      sA[(kc * 4 + 2) * DIM + n] = v.z;
      sA[(kc * 4 + 3) * DIM + n] = v.w;
      sW4w[flat] = Wk4[kb * 2048 + flat];
    }
    __syncthreads();

#pragma unroll 4
    for (int kl = 0; kl < 64; ++kl) {
      float4 a0 = sA4[kl * 32 + ty * 2];
      float4 a1 = sA4[kl * 32 + ty * 2 + 1];
      float4 w0 = sW4[kl * 32 + tx];
      float4 w1 = sW4[kl * 32 + 16 + tx];
      float a[8] = {a0.x, a0.y, a0.z, a0.w, a1.x, a1.y, a1.z, a1.w};
#pragma unroll
      for (int j = 0; j < 8; ++j) {
        acc[j].x += a[j] * w0.x;
        acc[j].y += a[j] * w0.y;
        acc[j].z += a[j] * w0.z;
        acc[j].w += a[j] * w0.w;
        acc2[j].x += a[j] * w1.x;
        acc2[j].y += a[j] * w1.y;
        acc2[j].z += a[j] * w1.z;
        acc2[j].w += a[j] * w1.w;
      }
    }
  }

  // Epilogue: e-partial per (node j, this thread's 8 cols), reduce over tx.
  float4 we0 = reinterpret_cast<const float4*>(w_e)[tx];
  float4 we1 = reinterpret_cast<const float4*>(w_e)[16 + tx];
  const float4* q4 = reinterpret_cast<const float4*>(q);
#pragma unroll
  for (int j = 0; j < 8; ++j) {
    int n = ty * 8 + j;
    int s = seg[base + n];
    float4 qa = q4[s * 32 + tx];
    float4 qb = q4[s * 32 + 16 + tx];
    float p = sigf(acc[j].x + qa.x) * we0.x + sigf(acc[j].y + qa.y) * we0.y +
              sigf(acc[j].z + qa.z) * we0.z + sigf(acc[j].w + qa.w) * we0.w +
              sigf(acc2[j].x + qb.x) * we1.x + sigf(acc2[j].y + qb.y) * we1.y +
              sigf(acc2[j].z + qb.z) * we1.z + sigf(acc2[j].w + qb.w) * we1.w;
#pragma unroll
    for (int off = 8; off >= 1; off >>= 1) p += __shfl_xor(p, off, 16);
    if (tx == 0) e[base + n] = p + __logf(cnt[base + n]);
  }
}

// ---------------------------------------------------------------------------
// Kernel 3: per-graph segment softmax + weighted sum of feat_i.
// One block (256 thr) per graph; segments contiguous (segment_ids sorted).
// ---------------------------------------------------------------------------
__global__ __launch_bounds__(256) void skernel(
    const float* __restrict__ feat, const int* __restrict__ seg,
    float* __restrict__ e, float* __restrict__ rst) {
  const int b = blockIdx.x;
  const int tid = threadIdx.x;

  // lower_bound boundaries (uniform across block, ~18 broadcast loads each)
  int lo = 0, hi = N_NODES;
  while (lo < hi) {
    int mid = (lo + hi) >> 1;
    if (seg[mid] < b) lo = mid + 1; else hi = mid;
  }
  const int s0 = lo;
  hi = N_NODES;
  while (lo < hi) {
    int mid = (lo + hi) >> 1;
    if (seg[mid] < b + 1) lo = mid + 1; else hi = mid;
  }
  const int s1 = lo;

  if (s1 <= s0) {  // empty segment -> zero row
    if (tid < DIM) rst[b * DIM + tid] = 0.0f;
    return;
  }

  __shared__ float red[8];
  __shared__ float part[8 * DIM];
  const int wave = tid >> 6, lane = tid & 63;

  // Phase 1: segment max
  float lm = -3.0e38f;
  for (int i = s0 + tid; i < s1; i += 256) lm = fmaxf(lm, e[i]);
#pragma unroll
  for (int off = 32; off >= 1; off >>= 1) lm = fmaxf(lm, __shfl_xor(lm, off, 64));
  if (lane == 0) red[wave] = lm;
  __syncthreads();
  const float m = fmaxf(fmaxf(red[0], red[1]), fmaxf(red[2], red[3]));

  // Phase 2: sum of exp (store p back into e)
  float ls = 0.0f;
  for (int i = s0 + tid; i < s1; i += 256) {
    float p = __expf(e[i] - m);
    e[i] = p;
    ls += p;
  }
#pragma unroll
  for (int off = 32; off >= 1; off >>= 1) ls += __shfl_xor(ls, off, 64);
  if (lane == 0) red[4 + wave] = ls;
  __syncthreads();
  const float inv = 1.0f / (red[4] + red[5] + red[6] + red[7]);

  // Phase 3: rst[b][:] = inv * sum_n p[n] * feat[n][:]
  const int c = tid & 31;   // float4 column chunk
  const int h = tid >> 5;   // 0..7 node-phase
  float4 acc = float4{0.f, 0.f, 0.f, 0.f};
  const float4* feat4 = reinterpret_cast<const float4*>(feat);
  for (int n = s0 + h; n < s1; n += 8) {
    float p = e[n];
    float4 f = feat4[n * 32 + c];
    acc.x += p * f.x;
    acc.y += p * f.y;
    acc.z += p * f.z;
    acc.w += p * f.w;
  }
  reinterpret_cast<float4*>(part)[h * 32 + c] = acc;
  __syncthreads();
  if (tid < DIM) {
    float tot = 0.0f;
#pragma unroll
    for (int hh = 0; hh < 8; ++hh) tot += part[hh * DIM + tid];
    rst[b * DIM + tid] = tot * inv;
  }
}

// ---------------------------------------------------------------------------
extern "C" void kernel_launch(void* const* d_in, const int* in_sizes, int n_in,
                              void* d_out, int out_size, void* d_ws,
                              size_t ws_size, hipStream_t stream) {
  const float* feat = (const float*)d_in[0];
  const float* U_feat = (const float*)d_in[1];
  const float* cnt = (const float*)d_in[2];
  const float* W_key = (const float*)d_in[3];
  const float* W_user = (const float*)d_in[4];
  const float* b_user = (const float*)d_in[5];
  const float* W_last = (const float*)d_in[6];
  const float* w_e = (const float*)d_in[7];
  const int* last_nodes = (const int*)d_in[8];
  const int* seg = (const int*)d_in[9];
  float* out = (float*)d_out;

  float* q = (float*)d_ws;            // B*D floats (2 MB)
  float* e = q + B_GRAPHS * DIM;      // N floats (0.82 MB)

  qkernel<<<B_GRAPHS / 8, 128, 0, stream>>>(feat, U_feat, W_user, b_user,
                                            W_last, last_nodes, q);
  ekernel<<<N_NODES / 128, 256, 0, stream>>>(feat, W_key, w_e, cnt, seg, q, e);
  skernel<<<B_GRAPHS, 256, 0, stream>>>(feat, seg, e, out);
}

// Round 2
// 94.275 us; speedup vs baseline: 1.6186x; 1.6186x over previous
//
#include <hip/hip_runtime.h>
#include <math.h>

#define N_NODES 204800
#define B_GRAPHS 4096
#define DIM 128

typedef __attribute__((ext_vector_type(8))) short bf16x8;
typedef __attribute__((ext_vector_type(4))) float f32x4;

__device__ __forceinline__ float sigf(float x) {
    return 1.0f / (1.0f + __expf(-x));
}

// round-to-nearest-even fp32 -> bf16 (inputs are normal floats; no NaN handling)
__device__ __forceinline__ unsigned short bfrne(float x) {
    unsigned u = __float_as_uint(x);
    unsigned r = u + 0x7FFFu + ((u >> 16) & 1u);
    return (unsigned short)(r >> 16);
}

// ---------------------------------------------------------------------------
// Kernel 1 (blocks 0..511): q[b] = U_feat[b]@W_user + b_user + feat[last[b]]@W_last
// Kernel 1 (blocks 512..575): Wt_bf16[c][k] = bf16(W_key[k][c])  (for ekernel)
// ---------------------------------------------------------------------------
__global__ __launch_bounds__(128) void qkernel(
    const float* __restrict__ feat, const float* __restrict__ U_feat,
    const float* __restrict__ W_user, const float* __restrict__ b_user,
    const float* __restrict__ W_last, const int* __restrict__ last_nodes,
    const float* __restrict__ W_key, unsigned short* __restrict__ Wt,
    float* __restrict__ q) {
  if (blockIdx.x >= 512) {
    int b = blockIdx.x - 512;  // 0..63
#pragma unroll
    for (int j = 0; j < 2; ++j) {
      int o = b * 256 + j * 128 + threadIdx.x;  // halfword index in Wt
      int c = o >> 7, k = o & 127;
      Wt[o] = bfrne(W_key[k * DIM + c]);
    }
    return;
  }
  __shared__ float sU[8][DIM];
  __shared__ float sL[8][DIM];
  const int d = threadIdx.x;
  const int g0 = blockIdx.x * 8;
  for (int g = 0; g < 8; ++g) {
    sU[g][d] = U_feat[(g0 + g) * DIM + d];
    int ln = last_nodes[g0 + g];
    sL[g][d] = feat[ln * DIM + d];
  }
  __syncthreads();
  float acc[8];
#pragma unroll
  for (int g = 0; g < 8; ++g) acc[g] = 0.0f;

  for (int kk = 0; kk < 32; ++kk) {
    float wu[4], wl[4];
#pragma unroll
    for (int j = 0; j < 4; ++j) {
      wu[j] = W_user[(kk * 4 + j) * DIM + d];
      wl[j] = W_last[(kk * 4 + j) * DIM + d];
    }
#pragma unroll
    for (int g = 0; g < 8; ++g) {
      float4 u4 = reinterpret_cast<const float4*>(sU[g])[kk];
      float4 l4 = reinterpret_cast<const float4*>(sL[g])[kk];
      acc[g] += u4.x * wu[0] + u4.y * wu[1] + u4.z * wu[2] + u4.w * wu[3];
      acc[g] += l4.x * wl[0] + l4.y * wl[1] + l4.z * wl[2] + l4.w * wl[3];
    }
  }
  float bu = b_user[d];
  for (int g = 0; g < 8; ++g) q[(g0 + g) * DIM + d] = acc[g] + bu;
}

// ---------------------------------------------------------------------------
// Kernel 2: e[n] = sigmoid(q[seg[n]] + (feat[n] @ W_key)) . w_e + log(cnt[n])
// bf16 MFMA version. 1600 blocks x 256 thr (4 waves). Per block: 128 nodes.
// LDS: A bf16 [128 nodes][128 k] + Wt bf16 [128 col][128 k], both XOR-swizzled
// (halfword idx ^= (row&7)<<3) so staging writes and b128 fragment reads are
// conflict-free. Wave w: nodes [32w,32w+32) = M-tiles {2w,2w+1} x 8 N-tiles.
// ---------------------------------------------------------------------------
__global__ __launch_bounds__(256) void ekernel(
    const float* __restrict__ feat, const unsigned short* __restrict__ Wt,
    const float* __restrict__ w_e, const float* __restrict__ cnt,
    const int* __restrict__ seg, const float* __restrict__ q,
    float* __restrict__ e) {
  __shared__ unsigned short sA[128 * 128];
  __shared__ unsigned short sW[128 * 128];
  const int tid = threadIdx.x;
  const int base = blockIdx.x * 128;

  // ---- stage A (fp32 -> bf16), 4KB-contiguous global reads per wave-iter
  const float4* feat4 = reinterpret_cast<const float4*>(feat + (size_t)base * DIM);
#pragma unroll
  for (int i = 0; i < 16; ++i) {
    int idx = i * 256 + tid;      // float4 index in tile (128 rows x 32 chunks)
    int row = idx >> 5, ch = idx & 31;
    float4 v = feat4[idx];
    ushort4 b;
    b.x = bfrne(v.x); b.y = bfrne(v.y); b.z = bfrne(v.z); b.w = bfrne(v.w);
    int hw = row * DIM + ((ch * 4) ^ ((row & 7) << 3));
    *reinterpret_cast<ushort4*>(&sA[hw]) = b;
  }
  // ---- stage Wt (already bf16 in ws), linear 16B loads -> swizzled stores
  const uint4* Wt4 = reinterpret_cast<const uint4*>(Wt);
#pragma unroll
  for (int i = 0; i < 8; ++i) {
    int hw = i * 2048 + tid * 8;  // 8 halfwords = 16B
    int row = hw >> 7, k0 = hw & 127;
    uint4 wv = Wt4[i * 256 + tid];
    int shw = row * DIM + (k0 ^ ((row & 7) << 3));
    *reinterpret_cast<uint4*>(&sW[shw]) = wv;
  }
  __syncthreads();

  const int l = tid & 63, w = tid >> 6;
  const int lr = l & 15, lh = l >> 4;  // lh = 0..3

  f32x4 acc[2][8];
#pragma unroll
  for (int m = 0; m < 2; ++m)
#pragma unroll
    for (int n = 0; n < 8; ++n) acc[m][n] = f32x4{0.f, 0.f, 0.f, 0.f};

#pragma unroll
  for (int ks = 0; ks < 4; ++ks) {
    const int kbase = ks * 32 + 8 * lh;
    bf16x8 af[2];
#pragma unroll
    for (int m = 0; m < 2; ++m) {
      int row = w * 32 + m * 16 + lr;
      af[m] = *reinterpret_cast<const bf16x8*>(
          &sA[row * DIM + (kbase ^ ((row & 7) << 3))]);
    }
#pragma unroll
    for (int n = 0; n < 8; ++n) {
      int col = n * 16 + lr;
      bf16x8 bf = *reinterpret_cast<const bf16x8*>(
          &sW[col * DIM + (kbase ^ ((col & 7) << 3))]);
      acc[0][n] = __builtin_amdgcn_mfma_f32_16x16x32_bf16(af[0], bf, acc[0][n], 0, 0, 0);
      acc[1][n] = __builtin_amdgcn_mfma_f32_16x16x32_bf16(af[1], bf, acc[1][n], 0, 0, 0);
    }
  }

  // ---- epilogue: e[node] = sum_c sigmoid(fk + q[s][c]) * w_e[c] + log(cnt)
  // D layout: col = n*16 + lr, row(node-in-tile) = w*32 + m*16 + 4*lh + r
  float we[8];
#pragma unroll
  for (int n = 0; n < 8; ++n) we[n] = w_e[n * 16 + lr];

#pragma unroll
  for (int m = 0; m < 2; ++m) {
#pragma unroll
    for (int r = 0; r < 4; ++r) {
      int node = base + w * 32 + m * 16 + 4 * lh + r;
      int s = seg[node];
      const float* qrow = q + (size_t)s * DIM;
      float p = 0.0f;
#pragma unroll
      for (int n = 0; n < 8; ++n) {
        float fk = acc[m][n][r];
        p += we[n] * sigf(fk + qrow[n * 16 + lr]);
      }
#pragma unroll
      for (int off = 8; off >= 1; off >>= 1) p += __shfl_xor(p, off, 16);
      if (lr == 0) e[node] = p + __logf(cnt[node]);
    }
  }
}

// ---------------------------------------------------------------------------
// Kernel 3: per-graph segment softmax + weighted sum of feat_i.
// ---------------------------------------------------------------------------
__global__ __launch_bounds__(256) void skernel(
    const float* __restrict__ feat, const int* __restrict__ seg,
    float* __restrict__ e, float* __restrict__ rst) {
  const int b = blockIdx.x;
  const int tid = threadIdx.x;

  int lo = 0, hi = N_NODES;
  while (lo < hi) {
    int mid = (lo + hi) >> 1;
    if (seg[mid] < b) lo = mid + 1; else hi = mid;
  }
  const int s0 = lo;
  hi = N_NODES;
  while (lo < hi) {
    int mid = (lo + hi) >> 1;
    if (seg[mid] < b + 1) lo = mid + 1; else hi = mid;
  }
  const int s1 = lo;

  if (s1 <= s0) {
    if (tid < DIM) rst[b * DIM + tid] = 0.0f;
    return;
  }

  __shared__ float red[8];
  __shared__ float part[8 * DIM];
  const int wave = tid >> 6, lane = tid & 63;

  float lm = -3.0e38f;
  for (int i = s0 + tid; i < s1; i += 256) lm = fmaxf(lm, e[i]);
#pragma unroll
  for (int off = 32; off >= 1; off >>= 1) lm = fmaxf(lm, __shfl_xor(lm, off, 64));
  if (lane == 0) red[wave] = lm;
  __syncthreads();
  const float m = fmaxf(fmaxf(red[0], red[1]), fmaxf(red[2], red[3]));

  float ls = 0.0f;
  for (int i = s0 + tid; i < s1; i += 256) {
    float p = __expf(e[i] - m);
    e[i] = p;
    ls += p;
  }
#pragma unroll
  for (int off = 32; off >= 1; off >>= 1) ls += __shfl_xor(ls, off, 64);
  if (lane == 0) red[4 + wave] = ls;
  __syncthreads();
  const float inv = 1.0f / (red[4] + red[5] + red[6] + red[7]);

  const int c = tid & 31;
  const int h = tid >> 5;
  float4 acc = float4{0.f, 0.f, 0.f, 0.f};
  const float4* feat4 = reinterpret_cast<const float4*>(feat);
  for (int n = s0 + h; n < s1; n += 8) {
    float p = e[n];
    float4 f = feat4[n * 32 + c];
    acc.x += p * f.x;
    acc.y += p * f.y;
    acc.z += p * f.z;
    acc.w += p * f.w;
  }
  reinterpret_cast<float4*>(part)[h * 32 + c] = acc;
  __syncthreads();
  if (tid < DIM) {
    float tot = 0.0f;
#pragma unroll
    for (int hh = 0; hh < 8; ++hh) tot += part[hh * DIM + tid];
    rst[b * DIM + tid] = tot * inv;
  }
}

// ---------------------------------------------------------------------------
extern "C" void kernel_launch(void* const* d_in, const int* in_sizes, int n_in,
                              void* d_out, int out_size, void* d_ws,
                              size_t ws_size, hipStream_t stream) {
  const float* feat = (const float*)d_in[0];
  const float* U_feat = (const float*)d_in[1];
  const float* cnt = (const float*)d_in[2];
  const float* W_key = (const float*)d_in[3];
  const float* W_user = (const float*)d_in[4];
  const float* b_user = (const float*)d_in[5];
  const float* W_last = (const float*)d_in[6];
  const float* w_e = (const float*)d_in[7];
  const int* last_nodes = (const int*)d_in[8];
  const int* seg = (const int*)d_in[9];
  float* out = (float*)d_out;

  float* q = (float*)d_ws;                       // B*D floats (2 MB)
  float* e = q + B_GRAPHS * DIM;                 // N floats (0.82 MB)
  unsigned short* Wt = (unsigned short*)(e + N_NODES);  // 128*128 bf16 (32 KB)

  qkernel<<<512 + 64, 128, 0, stream>>>(feat, U_feat, W_user, b_user, W_last,
                                        last_nodes, W_key, Wt, q);
  ekernel<<<N_NODES / 128, 256, 0, stream>>>(feat, Wt, w_e, cnt, seg, q, e);
  skernel<<<B_GRAPHS, 256, 0, stream>>>(feat, seg, e, out);
}

// Round 3
// 89.102 us; speedup vs baseline: 1.7126x; 1.0581x over previous
//
#include <hip/hip_runtime.h>
#include <hip/hip_bf16.h>
#include <math.h>

#define N_NODES 204800
#define B_GRAPHS 4096
#define DIM 128

typedef __attribute__((ext_vector_type(8))) short bf16x8;
typedef __attribute__((ext_vector_type(4))) float f32x4;

__device__ __forceinline__ float sigf(float x) {
    return 1.0f / (1.0f + __expf(-x));
}

// round-to-nearest-even fp32 -> bf16
__device__ __forceinline__ unsigned short bfrne(float x) {
    unsigned u = __float_as_uint(x);
    unsigned r = u + 0x7FFFu + ((u >> 16) & 1u);
    return (unsigned short)(r >> 16);
}

// ---------------------------------------------------------------------------
// Kernel 1 (blocks 0..511): q[b] = U_feat[b]@W_user + b_user + feat[last[b]]@W_last
// Kernel 1 (blocks 512..575): Wt_bf16[c][k] = bf16(W_key[k][c])  (for ekernel)
// ---------------------------------------------------------------------------
__global__ __launch_bounds__(128) void qkernel(
    const float* __restrict__ feat, const float* __restrict__ U_feat,
    const float* __restrict__ W_user, const float* __restrict__ b_user,
    const float* __restrict__ W_last, const int* __restrict__ last_nodes,
    const float* __restrict__ W_key, unsigned short* __restrict__ Wt,
    float* __restrict__ q) {
  if (blockIdx.x >= 512) {
    int b = blockIdx.x - 512;  // 0..63
#pragma unroll
    for (int j = 0; j < 2; ++j) {
      int o = b * 256 + j * 128 + threadIdx.x;  // halfword index in Wt
      int c = o >> 7, k = o & 127;
      Wt[o] = bfrne(W_key[k * DIM + c]);
    }
    return;
  }
  __shared__ float sU[8][DIM];
  __shared__ float sL[8][DIM];
  const int d = threadIdx.x;
  const int g0 = blockIdx.x * 8;
  for (int g = 0; g < 8; ++g) {
    sU[g][d] = U_feat[(g0 + g) * DIM + d];
    int ln = last_nodes[g0 + g];
    sL[g][d] = feat[ln * DIM + d];
  }
  __syncthreads();
  float acc[8];
#pragma unroll
  for (int g = 0; g < 8; ++g) acc[g] = 0.0f;

  for (int kk = 0; kk < 32; ++kk) {
    float wu[4], wl[4];
#pragma unroll
    for (int j = 0; j < 4; ++j) {
      wu[j] = W_user[(kk * 4 + j) * DIM + d];
      wl[j] = W_last[(kk * 4 + j) * DIM + d];
    }
#pragma unroll
    for (int g = 0; g < 8; ++g) {
      float4 u4 = reinterpret_cast<const float4*>(sU[g])[kk];
      float4 l4 = reinterpret_cast<const float4*>(sL[g])[kk];
      acc[g] += u4.x * wu[0] + u4.y * wu[1] + u4.z * wu[2] + u4.w * wu[3];
      acc[g] += l4.x * wl[0] + l4.y * wl[1] + l4.z * wl[2] + l4.w * wl[3];
    }
  }
  float bu = b_user[d];
  for (int g = 0; g < 8; ++g) q[(g0 + g) * DIM + d] = acc[g] + bu;
}

// ---------------------------------------------------------------------------
// Kernel 2: e[n] = sigmoid(q[seg[n]] + (feat[n] @ W_key)) . w_e + log(cnt[n])
// No A-LDS: each wave loads its A fragments straight from global (32B/lane,
// coalesced, each feat row touched exactly once) and converts fp32->bf16 in
// registers. LDS holds only W (32KB, XOR-swizzled). acc reused per n-tile;
// sigmoid.w_e partial carried across n-tiles => tiny register footprint.
// 1600 blocks x 256 thr; wave w owns nodes [32w, 32w+32) (2 m-tiles).
// ---------------------------------------------------------------------------
__global__ __launch_bounds__(256) void ekernel(
    const float* __restrict__ feat, const unsigned short* __restrict__ Wt,
    const float* __restrict__ w_e, const float* __restrict__ cnt,
    const int* __restrict__ seg, const float* __restrict__ q,
    float* __restrict__ e) {
  __shared__ unsigned short sW[128 * DIM];
  const int tid = threadIdx.x;
  const int base = blockIdx.x * 128;

  // ---- stage Wt (bf16 in ws), linear 16B loads -> swizzled stores
  const uint4* Wt4 = reinterpret_cast<const uint4*>(Wt);
#pragma unroll
  for (int i = 0; i < 8; ++i) {
    int hw = i * 2048 + tid * 8;  // 8 halfwords = 16B
    int row = hw >> 7, k0 = hw & 127;
    uint4 wv = Wt4[i * 256 + tid];
    *reinterpret_cast<uint4*>(&sW[row * DIM + (k0 ^ ((row & 7) << 3))]) = wv;
  }

  const int l = tid & 63, w = tid >> 6;
  const int lr = l & 15, lh = l >> 4;  // lane -> (row/col in tile, k-group)

  // ---- A fragments direct from global: lane holds row (l&15), k = 32ks+8lh..+8
  bf16x8 af[2][4];
#pragma unroll
  for (int m = 0; m < 2; ++m) {
    const float* rp =
        feat + (size_t)(base + w * 32 + m * 16 + lr) * DIM + lh * 8;
#pragma unroll
    for (int ks = 0; ks < 4; ++ks) {
      float4 v0 = *reinterpret_cast<const float4*>(rp + ks * 32);
      float4 v1 = *reinterpret_cast<const float4*>(rp + ks * 32 + 4);
      union { bf16x8 v; unsigned short u[8]; } a;
      a.u[0] = __bfloat16_as_ushort(__float2bfloat16(v0.x));
      a.u[1] = __bfloat16_as_ushort(__float2bfloat16(v0.y));
      a.u[2] = __bfloat16_as_ushort(__float2bfloat16(v0.z));
      a.u[3] = __bfloat16_as_ushort(__float2bfloat16(v0.w));
      a.u[4] = __bfloat16_as_ushort(__float2bfloat16(v1.x));
      a.u[5] = __bfloat16_as_ushort(__float2bfloat16(v1.y));
      a.u[6] = __bfloat16_as_ushort(__float2bfloat16(v1.z));
      a.u[7] = __bfloat16_as_ushort(__float2bfloat16(v1.w));
      af[m][ks] = a.v;
    }
  }

  // ---- per-lane w_e and per-(m,r) segment ids
  float we[8];
#pragma unroll
  for (int n = 0; n < 8; ++n) we[n] = w_e[n * 16 + lr];
  int sg[2][4];
#pragma unroll
  for (int m = 0; m < 2; ++m)
#pragma unroll
    for (int r = 0; r < 4; ++r)
      sg[m][r] = seg[base + w * 32 + m * 16 + 4 * lh + r];

  __syncthreads();

  float p[2][4];
#pragma unroll
  for (int m = 0; m < 2; ++m)
#pragma unroll
    for (int r = 0; r < 4; ++r) p[m][r] = 0.0f;

#pragma unroll
  for (int n = 0; n < 8; ++n) {
    const int col = n * 16 + lr;
    bf16x8 bfr[4];
#pragma unroll
    for (int ks = 0; ks < 4; ++ks)
      bfr[ks] = *reinterpret_cast<const bf16x8*>(
          &sW[col * DIM + ((ks * 32 + lh * 8) ^ ((col & 7) << 3))]);

    f32x4 acc[2];
    acc[0] = f32x4{0.f, 0.f, 0.f, 0.f};
    acc[1] = f32x4{0.f, 0.f, 0.f, 0.f};
#pragma unroll
    for (int ks = 0; ks < 4; ++ks) {
      acc[0] = __builtin_amdgcn_mfma_f32_16x16x32_bf16(af[0][ks], bfr[ks], acc[0], 0, 0, 0);
      acc[1] = __builtin_amdgcn_mfma_f32_16x16x32_bf16(af[1][ks], bfr[ks], acc[1], 0, 0, 0);
    }

    // fold this n-tile into the per-node partial: D layout col=lr, row=4lh+r
#pragma unroll
    for (int m = 0; m < 2; ++m) {
#pragma unroll
      for (int r = 0; r < 4; ++r) {
        const float* qrow = q + (size_t)sg[m][r] * DIM;
        p[m][r] += we[n] * sigf(acc[m][r] + qrow[col]);
      }
    }
  }

  // ---- reduce over the 16 lr lanes, write e
#pragma unroll
  for (int m = 0; m < 2; ++m) {
#pragma unroll
    for (int r = 0; r < 4; ++r) {
      float v = p[m][r];
#pragma unroll
      for (int off = 8; off >= 1; off >>= 1) v += __shfl_xor(v, off, 16);
      if (lr == 0) {
        int node = base + w * 32 + m * 16 + 4 * lh + r;
        e[node] = v + __logf(cnt[node]);
      }
    }
  }
}

// ---------------------------------------------------------------------------
// Kernel 3: per-graph segment softmax + weighted sum of feat_i.
// ---------------------------------------------------------------------------
__global__ __launch_bounds__(256) void skernel(
    const float* __restrict__ feat, const int* __restrict__ seg,
    float* __restrict__ e, float* __restrict__ rst) {
  const int b = blockIdx.x;
  const int tid = threadIdx.x;

  int lo = 0, hi = N_NODES;
  while (lo < hi) {
    int mid = (lo + hi) >> 1;
    if (seg[mid] < b) lo = mid + 1; else hi = mid;
  }
  const int s0 = lo;
  hi = N_NODES;
  while (lo < hi) {
    int mid = (lo + hi) >> 1;
    if (seg[mid] < b + 1) lo = mid + 1; else hi = mid;
  }
  const int s1 = lo;

  if (s1 <= s0) {
    if (tid < DIM) rst[b * DIM + tid] = 0.0f;
    return;
  }

  __shared__ float red[8];
  __shared__ float part[8 * DIM];
  const int wave = tid >> 6, lane = tid & 63;

  float lm = -3.0e38f;
  for (int i = s0 + tid; i < s1; i += 256) lm = fmaxf(lm, e[i]);
#pragma unroll
  for (int off = 32; off >= 1; off >>= 1) lm = fmaxf(lm, __shfl_xor(lm, off, 64));
  if (lane == 0) red[wave] = lm;
  __syncthreads();
  const float m = fmaxf(fmaxf(red[0], red[1]), fmaxf(red[2], red[3]));

  float ls = 0.0f;
  for (int i = s0 + tid; i < s1; i += 256) {
    float p = __expf(e[i] - m);
    e[i] = p;
    ls += p;
  }
#pragma unroll
  for (int off = 32; off >= 1; off >>= 1) ls += __shfl_xor(ls, off, 64);
  if (lane == 0) red[4 + wave] = ls;
  __syncthreads();
  const float inv = 1.0f / (red[4] + red[5] + red[6] + red[7]);

  const int c = tid & 31;
  const int h = tid >> 5;
  float4 acc = float4{0.f, 0.f, 0.f, 0.f};
  const float4* feat4 = reinterpret_cast<const float4*>(feat);
  for (int n = s0 + h; n < s1; n += 8) {
    float p = e[n];
    float4 f = feat4[n * 32 + c];
    acc.x += p * f.x;
    acc.y += p * f.y;
    acc.z += p * f.z;
    acc.w += p * f.w;
  }
  reinterpret_cast<float4*>(part)[h * 32 + c] = acc;
  __syncthreads();
  if (tid < DIM) {
    float tot = 0.0f;
#pragma unroll
    for (int hh = 0; hh < 8; ++hh) tot += part[hh * DIM + tid];
    rst[b * DIM + tid] = tot * inv;
  }
}

// ---------------------------------------------------------------------------
extern "C" void kernel_launch(void* const* d_in, const int* in_sizes, int n_in,
                              void* d_out, int out_size, void* d_ws,
                              size_t ws_size, hipStream_t stream) {
  const float* feat = (const float*)d_in[0];
  const float* U_feat = (const float*)d_in[1];
  const float* cnt = (const float*)d_in[2];
  const float* W_key = (const float*)d_in[3];
  const float* W_user = (const float*)d_in[4];
  const float* b_user = (const float*)d_in[5];
  const float* W_last = (const float*)d_in[6];
  const float* w_e = (const float*)d_in[7];
  const int* last_nodes = (const int*)d_in[8];
  const int* seg = (const int*)d_in[9];
  float* out = (float*)d_out;

  float* q = (float*)d_ws;                       // B*D floats (2 MB)
  float* e = q + B_GRAPHS * DIM;                 // N floats (0.82 MB)
  unsigned short* Wt = (unsigned short*)(e + N_NODES);  // 128*128 bf16 (32 KB)

  qkernel<<<512 + 64, 128, 0, stream>>>(feat, U_feat, W_user, b_user, W_last,
                                        last_nodes, W_key, Wt, q);
  ekernel<<<N_NODES / 128, 256, 0, stream>>>(feat, Wt, w_e, cnt, seg, q, e);
  skernel<<<B_GRAPHS, 256, 0, stream>>>(feat, seg, e, out);
}

// Round 4
// 87.031 us; speedup vs baseline: 1.7533x; 1.0238x over previous
//
#include <hip/hip_runtime.h>
#include <hip/hip_bf16.h>
#include <math.h>

#define N_NODES 204800
#define B_GRAPHS 4096
#define DIM 128

typedef __attribute__((ext_vector_type(8))) short bf16x8;
typedef __attribute__((ext_vector_type(4))) float f32x4;

__device__ __forceinline__ float sigf(float x) {
    return 1.0f / (1.0f + __expf(-x));
}

// round-to-nearest-even fp32 -> bf16
__device__ __forceinline__ unsigned short bfrne(float x) {
    unsigned u = __float_as_uint(x);
    unsigned r = u + 0x7FFFu + ((u >> 16) & 1u);
    return (unsigned short)(r >> 16);
}

// ---------------------------------------------------------------------------
// Kernel 1, three independent jobs selected by blockIdx.x:
//   [0..512):    q[b] = U_feat[b]@W_user + b_user + feat[last[b]]@W_last
//   [512..576):  Wt_bf16[c][k] = bf16(W_key[k][c])
//   [576..2176): segment bounds scatter: bounds[b] = first node of graph b
// ---------------------------------------------------------------------------
__global__ __launch_bounds__(128) void qkernel(
    const float* __restrict__ feat, const float* __restrict__ U_feat,
    const float* __restrict__ W_user, const float* __restrict__ b_user,
    const float* __restrict__ W_last, const int* __restrict__ last_nodes,
    const float* __restrict__ W_key, unsigned short* __restrict__ Wt,
    const int* __restrict__ seg, int* __restrict__ bounds,
    float* __restrict__ q) {
  if (blockIdx.x >= 576) {
    int n = (blockIdx.x - 576) * 128 + threadIdx.x;
    int sc = seg[n];
    int sp = (n == 0) ? -1 : seg[n - 1];
    for (int b = sp + 1; b <= sc; ++b) bounds[b] = (b == 0) ? 0 : n;
    if (n == N_NODES - 1)
      for (int b = sc + 1; b <= B_GRAPHS; ++b) bounds[b] = N_NODES;
    return;
  }
  if (blockIdx.x >= 512) {
    int b = blockIdx.x - 512;  // 0..63
#pragma unroll
    for (int j = 0; j < 2; ++j) {
      int o = b * 256 + j * 128 + threadIdx.x;  // halfword index in Wt
      int c = o >> 7, k = o & 127;
      Wt[o] = bfrne(W_key[k * DIM + c]);
    }
    return;
  }
  __shared__ float sU[8][DIM];
  __shared__ float sL[8][DIM];
  const int d = threadIdx.x;
  const int g0 = blockIdx.x * 8;
  for (int g = 0; g < 8; ++g) {
    sU[g][d] = U_feat[(g0 + g) * DIM + d];
    int ln = last_nodes[g0 + g];
    sL[g][d] = feat[ln * DIM + d];
  }
  __syncthreads();
  float acc[8];
#pragma unroll
  for (int g = 0; g < 8; ++g) acc[g] = 0.0f;

  for (int kk = 0; kk < 32; ++kk) {
    float wu[4], wl[4];
#pragma unroll
    for (int j = 0; j < 4; ++j) {
      wu[j] = W_user[(kk * 4 + j) * DIM + d];
      wl[j] = W_last[(kk * 4 + j) * DIM + d];
    }
#pragma unroll
    for (int g = 0; g < 8; ++g) {
      float4 u4 = reinterpret_cast<const float4*>(sU[g])[kk];
      float4 l4 = reinterpret_cast<const float4*>(sL[g])[kk];
      acc[g] += u4.x * wu[0] + u4.y * wu[1] + u4.z * wu[2] + u4.w * wu[3];
      acc[g] += l4.x * wl[0] + l4.y * wl[1] + l4.z * wl[2] + l4.w * wl[3];
    }
  }
  float bu = b_user[d];
  for (int g = 0; g < 8; ++g) q[(g0 + g) * DIM + d] = acc[g] + bu;
}

// ---------------------------------------------------------------------------
// Kernel 2: e[n] = sigmoid(q[seg[n]] + (feat[n] @ W_key)) . w_e + log(cnt[n])
// Swapped-operand MFMA, zero LDS, no barrier. mfma(W_frag, feat_frag) gives
// D[keycol = 4*lh + reg][node = lr]: each lane's 4 acc elems are 4 CONSECUTIVE
// key-cols of one node -> q gather is one float4 per (c,t); e-reduce is 2
// shfl_xor (over lh). A fragments loaded直接 from global (coalesced 128B/row,
// each feat row touched once); W fragments from global (32KB, L1-resident,
// shared by all blocks). 1600 blocks x 256 thr; wave w owns nodes
// [32w, 32w+32) as 2 node-tiles of 16.
// ---------------------------------------------------------------------------
__global__ __launch_bounds__(256) void ekernel(
    const float* __restrict__ feat, const unsigned short* __restrict__ Wt,
    const float* __restrict__ w_e, const float* __restrict__ cnt,
    const int* __restrict__ seg, const float* __restrict__ q,
    float* __restrict__ e) {
  const int tid = threadIdx.x;
  const int base = blockIdx.x * 128;
  const int l = tid & 63, w = tid >> 6;
  const int lr = l & 15, lh = l >> 4;  // lr: node-in-tile / W-row; lh: k-group

  // ---- feat fragments direct from global: lane -> row (t*16+lr), k=ks*32+8lh
  bf16x8 af[2][4];
#pragma unroll
  for (int t = 0; t < 2; ++t) {
    const float* rp =
        feat + (size_t)(base + w * 32 + t * 16 + lr) * DIM + lh * 8;
#pragma unroll
    for (int ks = 0; ks < 4; ++ks) {
      float4 v0 = *reinterpret_cast<const float4*>(rp + ks * 32);
      float4 v1 = *reinterpret_cast<const float4*>(rp + ks * 32 + 4);
      union { bf16x8 v; unsigned short u[8]; } a;
      a.u[0] = bfrne(v0.x); a.u[1] = bfrne(v0.y);
      a.u[2] = bfrne(v0.z); a.u[3] = bfrne(v0.w);
      a.u[4] = bfrne(v1.x); a.u[5] = bfrne(v1.y);
      a.u[6] = bfrne(v1.z); a.u[7] = bfrne(v1.w);
      af[t][ks] = a.v;
    }
  }

  int sg[2];
#pragma unroll
  for (int t = 0; t < 2; ++t) sg[t] = seg[base + w * 32 + t * 16 + lr];

  const float4* q4p = reinterpret_cast<const float4*>(q);
  const float4* we4p = reinterpret_cast<const float4*>(w_e);

  float p0 = 0.0f, p1 = 0.0f;
#pragma unroll
  for (int c = 0; c < 8; ++c) {
    bf16x8 wf[4];
#pragma unroll
    for (int ks = 0; ks < 4; ++ks)
      wf[ks] = *reinterpret_cast<const bf16x8*>(
          &Wt[(c * 16 + lr) * DIM + ks * 32 + lh * 8]);
    float4 we = we4p[c * 4 + lh];
    float4 q0 = q4p[(size_t)sg[0] * 32 + c * 4 + lh];
    float4 q1 = q4p[(size_t)sg[1] * 32 + c * 4 + lh];

    f32x4 a0 = f32x4{0.f, 0.f, 0.f, 0.f};
    f32x4 a1 = f32x4{0.f, 0.f, 0.f, 0.f};
#pragma unroll
    for (int ks = 0; ks < 4; ++ks) {
      a0 = __builtin_amdgcn_mfma_f32_16x16x32_bf16(wf[ks], af[0][ks], a0, 0, 0, 0);
      a1 = __builtin_amdgcn_mfma_f32_16x16x32_bf16(wf[ks], af[1][ks], a1, 0, 0, 0);
    }
    p0 += we.x * sigf(a0[0] + q0.x) + we.y * sigf(a0[1] + q0.y) +
          we.z * sigf(a0[2] + q0.z) + we.w * sigf(a0[3] + q0.w);
    p1 += we.x * sigf(a1[0] + q1.x) + we.y * sigf(a1[1] + q1.y) +
          we.z * sigf(a1[2] + q1.z) + we.w * sigf(a1[3] + q1.w);
  }

  // reduce over lh (lanes l, l^16, l^32, l^48), lh==0 lanes write
  float pv[2] = {p0, p1};
#pragma unroll
  for (int t = 0; t < 2; ++t) {
    float v = pv[t];
    v += __shfl_xor(v, 16, 64);
    v += __shfl_xor(v, 32, 64);
    if (lh == 0) {
      int node = base + w * 32 + t * 16 + lr;
      e[node] = v + __logf(cnt[node]);
    }
  }
}

// ---------------------------------------------------------------------------
// Kernel 3: per-graph segment softmax + weighted sum of feat_i.
// Bounds precomputed -> no binary search.
// ---------------------------------------------------------------------------
__global__ __launch_bounds__(256) void skernel(
    const float* __restrict__ feat, const int* __restrict__ bounds,
    float* __restrict__ e, float* __restrict__ rst) {
  const int b = blockIdx.x;
  const int tid = threadIdx.x;
  const int s0 = bounds[b];
  const int s1 = bounds[b + 1];

  if (s1 <= s0) {
    if (tid < DIM) rst[b * DIM + tid] = 0.0f;
    return;
  }

  __shared__ float red[8];
  __shared__ float part[8 * DIM];
  const int wave = tid >> 6, lane = tid & 63;

  float lm = -3.0e38f;
  for (int i = s0 + tid; i < s1; i += 256) lm = fmaxf(lm, e[i]);
#pragma unroll
  for (int off = 32; off >= 1; off >>= 1) lm = fmaxf(lm, __shfl_xor(lm, off, 64));
  if (lane == 0) red[wave] = lm;
  __syncthreads();
  const float m = fmaxf(fmaxf(red[0], red[1]), fmaxf(red[2], red[3]));

  float ls = 0.0f;
  for (int i = s0 + tid; i < s1; i += 256) {
    float p = __expf(e[i] - m);
    e[i] = p;
    ls += p;
  }
#pragma unroll
  for (int off = 32; off >= 1; off >>= 1) ls += __shfl_xor(ls, off, 64);
  if (lane == 0) red[4 + wave] = ls;
  __syncthreads();
  const float inv = 1.0f / (red[4] + red[5] + red[6] + red[7]);

  const int c = tid & 31;
  const int h = tid >> 5;
  float4 acc = float4{0.f, 0.f, 0.f, 0.f};
  const float4* feat4 = reinterpret_cast<const float4*>(feat);
  for (int n = s0 + h; n < s1; n += 8) {
    float p = e[n];
    float4 f = feat4[n * 32 + c];
    acc.x += p * f.x;
    acc.y += p * f.y;
    acc.z += p * f.z;
    acc.w += p * f.w;
  }
  reinterpret_cast<float4*>(part)[h * 32 + c] = acc;
  __syncthreads();
  if (tid < DIM) {
    float tot = 0.0f;
#pragma unroll
    for (int hh = 0; hh < 8; ++hh) tot += part[hh * DIM + tid];
    rst[b * DIM + tid] = tot * inv;
  }
}

// ---------------------------------------------------------------------------
extern "C" void kernel_launch(void* const* d_in, const int* in_sizes, int n_in,
                              void* d_out, int out_size, void* d_ws,
                              size_t ws_size, hipStream_t stream) {
  const float* feat = (const float*)d_in[0];
  const float* U_feat = (const float*)d_in[1];
  const float* cnt = (const float*)d_in[2];
  const float* W_key = (const float*)d_in[3];
  const float* W_user = (const float*)d_in[4];
  const float* b_user = (const float*)d_in[5];
  const float* W_last = (const float*)d_in[6];
  const float* w_e = (const float*)d_in[7];
  const int* last_nodes = (const int*)d_in[8];
  const int* seg = (const int*)d_in[9];
  float* out = (float*)d_out;

  float* q = (float*)d_ws;                       // 4096*128 f32 (2 MB)
  float* e = q + B_GRAPHS * DIM;                 // 204800 f32 (0.82 MB)
  unsigned short* Wt = (unsigned short*)(e + N_NODES);   // 128*128 bf16 (32 KB)
  int* bounds = (int*)(Wt + DIM * DIM);          // 4097 ints

  qkernel<<<512 + 64 + N_NODES / 128, 128, 0, stream>>>(
      feat, U_feat, W_user, b_user, W_last, last_nodes, W_key, Wt, seg, bounds, q);
  ekernel<<<N_NODES / 128, 256, 0, stream>>>(feat, Wt, w_e, cnt, seg, q, e);
  skernel<<<B_GRAPHS, 256, 0, stream>>>(feat, bounds, e, out);
}

// Round 5
// 70.572 us; speedup vs baseline: 2.1622x; 1.2332x over previous
//
#include <hip/hip_runtime.h>
#include <hip/hip_bf16.h>
#include <math.h>

#define N_NODES 204800
#define B_GRAPHS 4096
#define DIM 128

typedef __attribute__((ext_vector_type(8))) short bf16x8;
typedef __attribute__((ext_vector_type(4))) float f32x4;

__device__ __forceinline__ float sigf(float x) {
    return 1.0f / (1.0f + __expf(-x));
}

// round-to-nearest-even fp32 -> bf16
__device__ __forceinline__ unsigned short bfrne(float x) {
    unsigned u = __float_as_uint(x);
    unsigned r = u + 0x7FFFu + ((u >> 16) & 1u);
    return (unsigned short)(r >> 16);
}

// ---------------------------------------------------------------------------
// Kernel 1, three independent jobs selected by blockIdx.x:
//   [0..512):    q[b] = U_feat[b]@W_user + b_user + feat[last[b]]@W_last
//   [512..576):  Wt_bf16[c][k] = bf16(W_key[k][c])
//   [576..2176): segment bounds scatter: bounds[b] = first node of graph b
// ---------------------------------------------------------------------------
__global__ __launch_bounds__(128) void qkernel(
    const float* __restrict__ feat, const float* __restrict__ U_feat,
    const float* __restrict__ W_user, const float* __restrict__ b_user,
    const float* __restrict__ W_last, const int* __restrict__ last_nodes,
    const float* __restrict__ W_key, unsigned short* __restrict__ Wt,
    const int* __restrict__ seg, int* __restrict__ bounds,
    float* __restrict__ q) {
  if (blockIdx.x >= 576) {
    int n = (blockIdx.x - 576) * 128 + threadIdx.x;
    int sc = seg[n];
    int sp = (n == 0) ? -1 : seg[n - 1];
    for (int b = sp + 1; b <= sc; ++b) bounds[b] = (b == 0) ? 0 : n;
    if (n == N_NODES - 1)
      for (int b = sc + 1; b <= B_GRAPHS; ++b) bounds[b] = N_NODES;
    return;
  }
  if (blockIdx.x >= 512) {
    int b = blockIdx.x - 512;  // 0..63
#pragma unroll
    for (int j = 0; j < 2; ++j) {
      int o = b * 256 + j * 128 + threadIdx.x;  // halfword index in Wt
      int c = o >> 7, k = o & 127;
      Wt[o] = bfrne(W_key[k * DIM + c]);
    }
    return;
  }
  __shared__ float sU[8][DIM];
  __shared__ float sL[8][DIM];
  const int d = threadIdx.x;
  const int g0 = blockIdx.x * 8;
  for (int g = 0; g < 8; ++g) {
    sU[g][d] = U_feat[(g0 + g) * DIM + d];
    int ln = last_nodes[g0 + g];
    sL[g][d] = feat[ln * DIM + d];
  }
  __syncthreads();
  float acc[8];
#pragma unroll
  for (int g = 0; g < 8; ++g) acc[g] = 0.0f;

  for (int kk = 0; kk < 32; ++kk) {
    float wu[4], wl[4];
#pragma unroll
    for (int j = 0; j < 4; ++j) {
      wu[j] = W_user[(kk * 4 + j) * DIM + d];
      wl[j] = W_last[(kk * 4 + j) * DIM + d];
    }
#pragma unroll
    for (int g = 0; g < 8; ++g) {
      float4 u4 = reinterpret_cast<const float4*>(sU[g])[kk];
      float4 l4 = reinterpret_cast<const float4*>(sL[g])[kk];
      acc[g] += u4.x * wu[0] + u4.y * wu[1] + u4.z * wu[2] + u4.w * wu[3];
      acc[g] += l4.x * wl[0] + l4.y * wl[1] + l4.z * wl[2] + l4.w * wl[3];
    }
  }
  float bu = b_user[d];
  for (int g = 0; g < 8; ++g) q[(g0 + g) * DIM + d] = acc[g] + bu;
}

// ---------------------------------------------------------------------------
// Kernel 2: e[n] = sigmoid(q[seg[n]] + (feat[n] @ W_key)) . w_e + log(cnt[n])
// MLP-restructured: all 16 feat loads batched up-front; full q-gather (16
// float4, L2-resident) prefetched to registers before the c-loop; W and w_e
// staged in LDS (swizzled, R2-verified) so inner-loop reads ride lgkmcnt and
// interleave with MFMA. Swapped-operand MFMA: D[keycol=4lh+reg][node=lr].
// 1600 blocks x 256 thr; wave w owns nodes [32w,32w+32) as 2 tiles of 16.
// ---------------------------------------------------------------------------
__global__ __launch_bounds__(256, 2) void ekernel(
    const float* __restrict__ feat, const unsigned short* __restrict__ Wt,
    const float* __restrict__ w_e, const float* __restrict__ cnt,
    const int* __restrict__ seg, const float* __restrict__ q,
    float* __restrict__ e) {
  __shared__ unsigned short sW[128 * DIM];
  __shared__ float sWe[DIM];
  const int tid = threadIdx.x;
  const int base = blockIdx.x * 128;
  const int l = tid & 63, w = tid >> 6;
  const int lr = l & 15, lh = l >> 4;

  // ---- seg ids first (q addresses depend on them)
  int sg[2];
#pragma unroll
  for (int t = 0; t < 2; ++t) sg[t] = seg[base + w * 32 + t * 16 + lr];

  // ---- batch all 16 feat loads
  float4 fv[2][4][2];
#pragma unroll
  for (int t = 0; t < 2; ++t) {
    const float* rp =
        feat + (size_t)(base + w * 32 + t * 16 + lr) * DIM + lh * 8;
#pragma unroll
    for (int ks = 0; ks < 4; ++ks) {
      fv[t][ks][0] = *reinterpret_cast<const float4*>(rp + ks * 32);
      fv[t][ks][1] = *reinterpret_cast<const float4*>(rp + ks * 32 + 4);
    }
  }

  // ---- prefetch the whole q gather (scattered 16B, L2-resident)
  const float4* q4p = reinterpret_cast<const float4*>(q);
  float4 qv[2][8];
#pragma unroll
  for (int t = 0; t < 2; ++t)
#pragma unroll
    for (int c = 0; c < 8; ++c)
      qv[t][c] = q4p[(size_t)sg[t] * 32 + c * 4 + lh];

  // ---- stage Wt + w_e into LDS
  const uint4* Wt4 = reinterpret_cast<const uint4*>(Wt);
#pragma unroll
  for (int i = 0; i < 8; ++i) {
    int hw = i * 2048 + tid * 8;
    int row = hw >> 7, k0 = hw & 127;
    uint4 wv = Wt4[i * 256 + tid];
    *reinterpret_cast<uint4*>(&sW[row * DIM + (k0 ^ ((row & 7) << 3))]) = wv;
  }
  if (tid < 32)
    reinterpret_cast<float4*>(sWe)[tid] =
        reinterpret_cast<const float4*>(w_e)[tid];

  // ---- convert feat to bf16 fragments (loads by now long in flight)
  bf16x8 af[2][4];
#pragma unroll
  for (int t = 0; t < 2; ++t)
#pragma unroll
    for (int ks = 0; ks < 4; ++ks) {
      union { bf16x8 v; unsigned short u[8]; } a;
      a.u[0] = bfrne(fv[t][ks][0].x); a.u[1] = bfrne(fv[t][ks][0].y);
      a.u[2] = bfrne(fv[t][ks][0].z); a.u[3] = bfrne(fv[t][ks][0].w);
      a.u[4] = bfrne(fv[t][ks][1].x); a.u[5] = bfrne(fv[t][ks][1].y);
      a.u[6] = bfrne(fv[t][ks][1].z); a.u[7] = bfrne(fv[t][ks][1].w);
      af[t][ks] = a.v;
    }

  __syncthreads();

  float p0 = 0.0f, p1 = 0.0f;
#pragma unroll
  for (int c = 0; c < 8; ++c) {
    const int row = c * 16 + lr;
    bf16x8 wf[4];
#pragma unroll
    for (int ks = 0; ks < 4; ++ks)
      wf[ks] = *reinterpret_cast<const bf16x8*>(
          &sW[row * DIM + ((ks * 32 + lh * 8) ^ ((row & 7) << 3))]);
    float4 we = *reinterpret_cast<const float4*>(&sWe[c * 16 + lh * 4]);

    f32x4 a0 = f32x4{0.f, 0.f, 0.f, 0.f};
    f32x4 a1 = f32x4{0.f, 0.f, 0.f, 0.f};
#pragma unroll
    for (int ks = 0; ks < 4; ++ks) {
      a0 = __builtin_amdgcn_mfma_f32_16x16x32_bf16(wf[ks], af[0][ks], a0, 0, 0, 0);
      a1 = __builtin_amdgcn_mfma_f32_16x16x32_bf16(wf[ks], af[1][ks], a1, 0, 0, 0);
    }
    float4 q0 = qv[0][c], q1 = qv[1][c];
    p0 += we.x * sigf(a0[0] + q0.x) + we.y * sigf(a0[1] + q0.y) +
          we.z * sigf(a0[2] + q0.z) + we.w * sigf(a0[3] + q0.w);
    p1 += we.x * sigf(a1[0] + q1.x) + we.y * sigf(a1[1] + q1.y) +
          we.z * sigf(a1[2] + q1.z) + we.w * sigf(a1[3] + q1.w);
  }

  // reduce over lh (lanes l, l^16, l^32), lh==0 lanes write
  float pv[2] = {p0, p1};
#pragma unroll
  for (int t = 0; t < 2; ++t) {
    float v = pv[t];
    v += __shfl_xor(v, 16, 64);
    v += __shfl_xor(v, 32, 64);
    if (lh == 0) {
      int node = base + w * 32 + t * 16 + lr;
      e[node] = v + __logf(cnt[node]);
    }
  }
}

// ---------------------------------------------------------------------------
// Kernel 3: per-graph segment softmax + weighted sum of feat_i.
// ---------------------------------------------------------------------------
__global__ __launch_bounds__(256) void skernel(
    const float* __restrict__ feat, const int* __restrict__ bounds,
    float* __restrict__ e, float* __restrict__ rst) {
  const int b = blockIdx.x;
  const int tid = threadIdx.x;
  const int s0 = bounds[b];
  const int s1 = bounds[b + 1];

  if (s1 <= s0) {
    if (tid < DIM) rst[b * DIM + tid] = 0.0f;
    return;
  }

  __shared__ float red[8];
  __shared__ float part[8 * DIM];
  const int wave = tid >> 6, lane = tid & 63;

  float lm = -3.0e38f;
  for (int i = s0 + tid; i < s1; i += 256) lm = fmaxf(lm, e[i]);
#pragma unroll
  for (int off = 32; off >= 1; off >>= 1) lm = fmaxf(lm, __shfl_xor(lm, off, 64));
  if (lane == 0) red[wave] = lm;
  __syncthreads();
  const float m = fmaxf(fmaxf(red[0], red[1]), fmaxf(red[2], red[3]));

  float ls = 0.0f;
  for (int i = s0 + tid; i < s1; i += 256) {
    float p = __expf(e[i] - m);
    e[i] = p;
    ls += p;
  }
#pragma unroll
  for (int off = 32; off >= 1; off >>= 1) ls += __shfl_xor(ls, off, 64);
  if (lane == 0) red[4 + wave] = ls;
  __syncthreads();
  const float inv = 1.0f / (red[4] + red[5] + red[6] + red[7]);

  const int c = tid & 31;
  const int h = tid >> 5;
  float4 acc = float4{0.f, 0.f, 0.f, 0.f};
  const float4* feat4 = reinterpret_cast<const float4*>(feat);
  for (int n = s0 + h; n < s1; n += 8) {
    float p = e[n];
    float4 f = feat4[n * 32 + c];
    acc.x += p * f.x;
    acc.y += p * f.y;
    acc.z += p * f.z;
    acc.w += p * f.w;
  }
  reinterpret_cast<float4*>(part)[h * 32 + c] = acc;
  __syncthreads();
  if (tid < DIM) {
    float tot = 0.0f;
#pragma unroll
    for (int hh = 0; hh < 8; ++hh) tot += part[hh * DIM + tid];
    rst[b * DIM + tid] = tot * inv;
  }
}

// ---------------------------------------------------------------------------
extern "C" void kernel_launch(void* const* d_in, const int* in_sizes, int n_in,
                              void* d_out, int out_size, void* d_ws,
                              size_t ws_size, hipStream_t stream) {
  const float* feat = (const float*)d_in[0];
  const float* U_feat = (const float*)d_in[1];
  const float* cnt = (const float*)d_in[2];
  const float* W_key = (const float*)d_in[3];
  const float* W_user = (const float*)d_in[4];
  const float* b_user = (const float*)d_in[5];
  const float* W_last = (const float*)d_in[6];
  const float* w_e = (const float*)d_in[7];
  const int* last_nodes = (const int*)d_in[8];
  const int* seg = (const int*)d_in[9];
  float* out = (float*)d_out;

  float* q = (float*)d_ws;                       // 4096*128 f32 (2 MB)
  float* e = q + B_GRAPHS * DIM;                 // 204800 f32 (0.82 MB)
  unsigned short* Wt = (unsigned short*)(e + N_NODES);   // 128*128 bf16 (32 KB)
  int* bounds = (int*)(Wt + DIM * DIM);          // 4097 ints

  qkernel<<<512 + 64 + N_NODES / 128, 128, 0, stream>>>(
      feat, U_feat, W_user, b_user, W_last, last_nodes, W_key, Wt, seg, bounds, q);
  ekernel<<<N_NODES / 128, 256, 0, stream>>>(feat, Wt, w_e, cnt, seg, q, e);
  skernel<<<B_GRAPHS, 256, 0, stream>>>(feat, bounds, e, out);
}